// Round 1
// baseline (374.116 us; speedup 1.0000x reference)
//
#include <hip/hip_runtime.h>
#include <stdint.h>

// Problem constants (reference: B=2, S=2048, D=1024, H=16, DK=64)
#define B_  2
#define S_  2048
#define D_  1024
#define H_  16
#define DK_ 64

typedef __attribute__((ext_vector_type(8))) short short8;   // 8 bf16 = 4 VGPRs (MFMA A/B frag)
typedef __attribute__((ext_vector_type(4))) float floatx4;  // MFMA C/D frag

#define MFMA16(a, b, c) __builtin_amdgcn_mfma_f32_16x16x32_bf16((a), (b), (c), 0, 0, 0)

// async global->LDS, 16B per lane. LDS dest = wave-uniform base + lane*16 (HW adds lane offset).
__device__ __forceinline__ void gload_lds16(const void* g, void* lds) {
  __builtin_amdgcn_global_load_lds(
      (__attribute__((address_space(1))) void*)(void*)g,
      (__attribute__((address_space(3))) void*)lds, 16, 0, 0);
}

// fp32 -> bf16 round-to-nearest-even (no NaN inputs expected here)
__device__ __forceinline__ unsigned short f2bf(float f) {
  union { float f; unsigned int u; } v;
  v.f = f;
  unsigned int r = v.u + 0x7fffu + ((v.u >> 16) & 1u);
  return (unsigned short)(r >> 16);
}

// ---------------- cast fp32 -> bf16, vectorized x4 ----------------
__global__ void cast_f32_bf16(const float* __restrict__ in, unsigned short* __restrict__ out, int n4) {
  int i = blockIdx.x * 256 + threadIdx.x;
  if (i < n4) {
    float4 f = ((const float4*)in)[i];
    uint2 p;
    p.x = (unsigned int)f2bf(f.x) | ((unsigned int)f2bf(f.y) << 16);
    p.y = (unsigned int)f2bf(f.z) | ((unsigned int)f2bf(f.w) << 16);
    ((uint2*)out)[i] = p;
  }
}

// ---------------- GEMM: C[M=4096][N=1024] = A[M][K=1024] * W[N][K]^T ----------------
// m97-style: 128x128 tile, BK=32, 4 waves each 64x64 (4x4 MFMA 16x16x32 tiles).
// MODE 0: store bf16 to head layout [b,h,s,dk]   (Q, K projections)
// MODE 1: store bf16 to Vt layout  [b,h,dk,s]    (V projection, pre-transposed for PV)
// MODE 2: store fp32 row-major [token][e]        (output projection)
template <int MODE>
__launch_bounds__(256, 2)
__global__ void gemm_bt(const unsigned short* __restrict__ A,
                        const unsigned short* __restrict__ Bw,
                        void* __restrict__ Out) {
  __shared__ unsigned short lA[128 * 32];
  __shared__ unsigned short lB[128 * 32];
  const int tid  = threadIdx.x;
  const int lane = tid & 63;
  const int wave = tid >> 6;
  const int m0 = blockIdx.y * 128;
  const int n0 = blockIdx.x * 128;
  const int K  = D_;
  const int wm = (wave >> 1) * 64;
  const int wn = (wave & 1) * 64;

  floatx4 acc[4][4] = {};

  for (int k0 = 0; k0 < K; k0 += 32) {
#pragma unroll
    for (int l = 0; l < 2; ++l) {
      int c = l * 256 + tid;          // 16B chunk id; tile = 128 rows x 64B, row-major
      int row = c >> 2, cb = (c & 3) * 16;
      const char* ga = (const char*)A + ((size_t)(m0 + row) * K + k0) * 2 + cb;
      gload_lds16(ga, (char*)lA + (size_t)(l * 256 + wave * 64) * 16);
      const char* gb = (const char*)Bw + ((size_t)(n0 + row) * K + k0) * 2 + cb;
      gload_lds16(gb, (char*)lB + (size_t)(l * 256 + wave * 64) * 16);
    }
    __syncthreads();

    short8 af[4], bf_[4];
#pragma unroll
    for (int mt = 0; mt < 4; ++mt)
      af[mt] = *(const short8*)&lA[(wm + mt * 16 + (lane & 15)) * 32 + (lane >> 4) * 8];
#pragma unroll
    for (int nt = 0; nt < 4; ++nt)
      bf_[nt] = *(const short8*)&lB[(wn + nt * 16 + (lane & 15)) * 32 + (lane >> 4) * 8];
#pragma unroll
    for (int mt = 0; mt < 4; ++mt)
#pragma unroll
      for (int nt = 0; nt < 4; ++nt)
        acc[mt][nt] = MFMA16(af[mt], bf_[nt], acc[mt][nt]);
    __syncthreads();
  }

  // epilogue — C/D layout: col = lane&15, row = (lane>>4)*4 + reg  [guide m89]
  if (MODE == 0) {
    unsigned short* O = (unsigned short*)Out;
#pragma unroll
    for (int mt = 0; mt < 4; ++mt)
#pragma unroll
      for (int nt = 0; nt < 4; ++nt)
#pragma unroll
        for (int r = 0; r < 4; ++r) {
          int row = m0 + wm + mt * 16 + (lane >> 4) * 4 + r;  // token
          int col = n0 + wn + nt * 16 + (lane & 15);          // e
          int b = row >> 11, s = row & (S_ - 1);
          int h = col >> 6,  dk = col & 63;
          O[((size_t)(b * H_ + h) * S_ + s) * DK_ + dk] = f2bf(acc[mt][nt][r]);
        }
  } else if (MODE == 1) {
    unsigned short* O = (unsigned short*)Out;
#pragma unroll
    for (int mt = 0; mt < 4; ++mt)
#pragma unroll
      for (int nt = 0; nt < 4; ++nt) {
        int row0 = m0 + wm + mt * 16 + (lane >> 4) * 4;  // token base (4 consecutive s)
        int col  = n0 + wn + nt * 16 + (lane & 15);
        int b = row0 >> 11, s0 = row0 & (S_ - 1);
        int h = col >> 6,   dk = col & 63;
        unsigned long long pk =
            (unsigned long long)f2bf(acc[mt][nt][0]) |
            ((unsigned long long)f2bf(acc[mt][nt][1]) << 16) |
            ((unsigned long long)f2bf(acc[mt][nt][2]) << 32) |
            ((unsigned long long)f2bf(acc[mt][nt][3]) << 48);
        *(unsigned long long*)&O[((size_t)(b * H_ + h) * DK_ + dk) * S_ + s0] = pk;
      }
  } else {
    float* O = (float*)Out;
#pragma unroll
    for (int mt = 0; mt < 4; ++mt)
#pragma unroll
      for (int nt = 0; nt < 4; ++nt)
#pragma unroll
        for (int r = 0; r < 4; ++r) {
          int row = m0 + wm + mt * 16 + (lane >> 4) * 4 + r;
          int col = n0 + wn + nt * 16 + (lane & 15);
          O[(size_t)row * D_ + col] = acc[mt][nt][r];
        }
  }
}

// ---------------- Pass 1: Zr[b,q,k] = 1 / sum_h exp(s[b,h,q,k]) ----------------
// block = (k-tile 64, q-tile 64, b); 4 waves, wave w owns q rows [w*16, w*16+16).
// Scores are tiny (std~0.41) so exp without max-subtraction is exact-safe.
__launch_bounds__(256, 2)
__global__ void compute_z(const unsigned short* __restrict__ Qh,
                          const unsigned short* __restrict__ Kh,
                          float* __restrict__ Zr) {
  __shared__ unsigned short lQ[64 * 64];
  __shared__ unsigned short lK[64 * 64];
  const int tid = threadIdx.x, lane = tid & 63, wave = tid >> 6;
  const int k0 = blockIdx.x * 64, q0 = blockIdx.y * 64, b = blockIdx.z;

  floatx4 zacc[4] = {};

  for (int h = 0; h < H_; ++h) {
    const unsigned short* qb = Qh + ((size_t)(b * H_ + h) * S_ + q0) * DK_;  // contiguous 8KB
    const unsigned short* kb = Kh + ((size_t)(b * H_ + h) * S_ + k0) * DK_;
#pragma unroll
    for (int l = 0; l < 2; ++l) {
      int c = l * 256 + tid;
      gload_lds16((const char*)qb + (size_t)c * 16, (char*)lQ + (size_t)(l * 256 + wave * 64) * 16);
      gload_lds16((const char*)kb + (size_t)c * 16, (char*)lK + (size_t)(l * 256 + wave * 64) * 16);
    }
    __syncthreads();

    floatx4 sacc[4] = {};
#pragma unroll
    for (int ks = 0; ks < 2; ++ks) {
      short8 a = *(const short8*)&lQ[(wave * 16 + (lane & 15)) * 64 + ks * 32 + (lane >> 4) * 8];
#pragma unroll
      for (int nt = 0; nt < 4; ++nt) {
        short8 bb = *(const short8*)&lK[(nt * 16 + (lane & 15)) * 64 + ks * 32 + (lane >> 4) * 8];
        sacc[nt] = MFMA16(a, bb, sacc[nt]);
      }
    }
#pragma unroll
    for (int nt = 0; nt < 4; ++nt)
#pragma unroll
      for (int r = 0; r < 4; ++r)
        zacc[nt][r] += __expf(sacc[nt][r] * 0.125f);  // 1/sqrt(64)
    __syncthreads();
  }

#pragma unroll
  for (int nt = 0; nt < 4; ++nt)
#pragma unroll
    for (int r = 0; r < 4; ++r) {
      int q = q0 + wave * 16 + (lane >> 4) * 4 + r;
      int k = k0 + nt * 16 + (lane & 15);
      Zr[((size_t)b * S_ + q) * S_ + k] = 1.0f / zacc[nt][r];
    }
}

// ---------------- Pass 2: x^T[b,h,:,:] = (exp(QK^T/8) .* Zr) @ V, written as X[b,s,h*64+dk] ----
// block = (q-tile 64, h, b); 4 waves. QK phase: wave w owns q rows [w*16,+16).
// PV computed as x^T (m=dk, n=q) so BOTH operands are contiguous ds_read_b128:
//   A = Vt[dk][k] rows, B[k][q] = P[q][k] rows.
__launch_bounds__(256, 2)
__global__ void attn_pv(const unsigned short* __restrict__ Qh,
                        const unsigned short* __restrict__ Kh,
                        const unsigned short* __restrict__ Vt,
                        const float* __restrict__ Zr,
                        unsigned short* __restrict__ X) {
  __shared__ unsigned short lQ[64 * 64];
  __shared__ unsigned short lK[64 * 64];
  __shared__ unsigned short lV[64 * 64];  // Vt tile: rows dk, cols k
  __shared__ unsigned short lP[64 * 64];  // rows q, cols k
  const int tid = threadIdx.x, lane = tid & 63, wave = tid >> 6;
  const int q0 = blockIdx.x * 64;
  const int h = blockIdx.y, b = blockIdx.z;

  const unsigned short* qb = Qh + ((size_t)(b * H_ + h) * S_ + q0) * DK_;
#pragma unroll
  for (int l = 0; l < 2; ++l) {
    int c = l * 256 + tid;
    gload_lds16((const char*)qb + (size_t)c * 16, (char*)lQ + (size_t)(l * 256 + wave * 64) * 16);
  }
  const unsigned short* kbase = Kh + (size_t)(b * H_ + h) * S_ * DK_;
  const unsigned short* vbase = Vt + (size_t)(b * H_ + h) * DK_ * S_;
  const float* zbase = Zr + ((size_t)b * S_ + q0) * S_;

  floatx4 xacc[4] = {};  // x^T: rows dk = wave*16.., cols q = nt*16..

  for (int kt = 0; kt < S_ / 64; ++kt) {
    int k0 = kt * 64;
#pragma unroll
    for (int l = 0; l < 2; ++l) {
      int c = l * 256 + tid;
      gload_lds16((const char*)(kbase + (size_t)k0 * DK_) + (size_t)c * 16,
                  (char*)lK + (size_t)(l * 256 + wave * 64) * 16);
      int vr = c >> 3, vcb = (c & 7) * 16;  // Vt tile: 64 rows x 128B, row stride S_*2 in global
      gload_lds16((const char*)(vbase + (size_t)vr * S_ + k0) + vcb,
                  (char*)lV + (size_t)(l * 256 + wave * 64) * 16);
    }
    // Z loads (independent of LDS) — issue before the barrier to overlap
    float zv[4][4];
#pragma unroll
    for (int nt = 0; nt < 4; ++nt)
#pragma unroll
      for (int r = 0; r < 4; ++r) {
        int q = wave * 16 + (lane >> 4) * 4 + r;
        int k = k0 + nt * 16 + (lane & 15);
        zv[nt][r] = zbase[(size_t)q * S_ + k];
      }
    __syncthreads();

    // S tile (wave's 16 q rows x 64 k)
    floatx4 sacc[4] = {};
#pragma unroll
    for (int ks = 0; ks < 2; ++ks) {
      short8 a = *(const short8*)&lQ[(wave * 16 + (lane & 15)) * 64 + ks * 32 + (lane >> 4) * 8];
#pragma unroll
      for (int nt = 0; nt < 4; ++nt) {
        short8 bb = *(const short8*)&lK[(nt * 16 + (lane & 15)) * 64 + ks * 32 + (lane >> 4) * 8];
        sacc[nt] = MFMA16(a, bb, sacc[nt]);
      }
    }
    // P = exp(s/8) * (1/Z)  -> lP[q][k] bf16
#pragma unroll
    for (int nt = 0; nt < 4; ++nt)
#pragma unroll
      for (int r = 0; r < 4; ++r) {
        int q = wave * 16 + (lane >> 4) * 4 + r;
        int k = nt * 16 + (lane & 15);
        lP[q * 64 + k] = f2bf(__expf(sacc[nt][r] * 0.125f) * zv[nt][r]);
      }
    __syncthreads();

    // x^T += Vt_tile @ P^T   (A rows = lV, B rows = lP, both contiguous)
#pragma unroll
    for (int ks = 0; ks < 2; ++ks) {
      short8 a = *(const short8*)&lV[(wave * 16 + (lane & 15)) * 64 + ks * 32 + (lane >> 4) * 8];
#pragma unroll
      for (int nt = 0; nt < 4; ++nt) {
        short8 bb = *(const short8*)&lP[(nt * 16 + (lane & 15)) * 64 + ks * 32 + (lane >> 4) * 8];
        xacc[nt] = MFMA16(a, bb, xacc[nt]);
      }
    }
    __syncthreads();
  }

  // transpose x^T -> x via LDS (reuse lQ), then coalesced bf16 store to X[b, s, h*64+dk]
#pragma unroll
  for (int nt = 0; nt < 4; ++nt)
#pragma unroll
    for (int r = 0; r < 4; ++r) {
      int q  = nt * 16 + (lane & 15);               // C/D col = n = q
      int dk = wave * 16 + (lane >> 4) * 4 + r;     // C/D row = m = dk
      lQ[q * 64 + dk] = f2bf(xacc[nt][r]);
    }
  __syncthreads();
  {
    int q = tid >> 2, cb = (tid & 3) * 16;
    short8 v0 = *(const short8*)&lQ[q * 64 + cb + 0];
    short8 v1 = *(const short8*)&lQ[q * 64 + cb + 8];
    unsigned short* o = X + (size_t)(b * S_ + q0 + q) * D_ + h * DK_ + cb;
    *(short8*)&o[0] = v0;
    *(short8*)&o[8] = v1;
  }
}

// ---------------- launch ----------------
extern "C" void kernel_launch(void* const* d_in, const int* in_sizes, int n_in,
                              void* d_out, int out_size, void* d_ws, size_t ws_size,
                              hipStream_t stream) {
  const float* qi = (const float*)d_in[0];
  const float* ki = (const float*)d_in[1];
  const float* vi = (const float*)d_in[2];
  // d_in[3] = mask: reference discards masked_fill result -> unused
  const float* Wq = (const float*)d_in[4];
  const float* Wk = (const float*)d_in[5];
  const float* Wv = (const float*)d_in[6];
  const float* Wo = (const float*)d_in[7];

  const size_t NT = (size_t)B_ * S_ * D_;  // 4,194,304
  const size_t NW = (size_t)D_ * D_;       // 1,048,576

  // workspace carve-out (~96 MiB total)
  unsigned short* w = (unsigned short*)d_ws;
  unsigned short* qi_bf = w; w += NT;
  unsigned short* ki_bf = w; w += NT;
  unsigned short* vi_bf = w; w += NT;
  unsigned short* Wq_bf = w; w += NW;
  unsigned short* Wk_bf = w; w += NW;
  unsigned short* Wv_bf = w; w += NW;
  unsigned short* Wo_bf = w; w += NW;
  unsigned short* Qh = w; w += NT;  // [b,h,s,dk]
  unsigned short* Kh = w; w += NT;  // [b,h,s,dk]
  unsigned short* Vt = w; w += NT;  // [b,h,dk,s]
  unsigned short* Xb = w; w += NT;  // [b,s,e]
  float* Zr = (float*)w;            // [b,q,k] fp32, 32 MiB

  {
    int n4 = (int)(NT / 4);
    int g = (n4 + 255) / 256;
    cast_f32_bf16<<<g, 256, 0, stream>>>(qi, qi_bf, n4);
    cast_f32_bf16<<<g, 256, 0, stream>>>(ki, ki_bf, n4);
    cast_f32_bf16<<<g, 256, 0, stream>>>(vi, vi_bf, n4);
    int n4w = (int)(NW / 4);
    int gw = (n4w + 255) / 256;
    cast_f32_bf16<<<gw, 256, 0, stream>>>(Wq, Wq_bf, n4w);
    cast_f32_bf16<<<gw, 256, 0, stream>>>(Wk, Wk_bf, n4w);
    cast_f32_bf16<<<gw, 256, 0, stream>>>(Wv, Wv_bf, n4w);
    cast_f32_bf16<<<gw, 256, 0, stream>>>(Wo, Wo_bf, n4w);
  }

  dim3 gg(D_ / 128, (B_ * S_) / 128);  // (8, 32)
  gemm_bt<0><<<gg, 256, 0, stream>>>(qi_bf, Wq_bf, Qh);
  gemm_bt<0><<<gg, 256, 0, stream>>>(ki_bf, Wk_bf, Kh);
  gemm_bt<1><<<gg, 256, 0, stream>>>(vi_bf, Wv_bf, Vt);

  compute_z<<<dim3(S_ / 64, S_ / 64, B_), 256, 0, stream>>>(Qh, Kh, Zr);
  attn_pv<<<dim3(S_ / 64, H_, B_), 256, 0, stream>>>(Qh, Kh, Vt, Zr, Xb);

  gemm_bt<2><<<gg, 256, 0, stream>>>(Xb, Wo_bf, d_out);
}

// Round 3
// 353.013 us; speedup vs baseline: 1.0598x; 1.0598x over previous
//
#include <hip/hip_runtime.h>
#include <stdint.h>

// Problem constants (reference: B=2, S=2048, D=1024, H=16, DK=64)
#define B_  2
#define S_  2048
#define D_  1024
#define H_  16
#define DK_ 64
#define PERHEAD (S_ * DK_)  // 131072 elems per (b,h)

typedef __attribute__((ext_vector_type(8))) short short8;   // 8 bf16 = 4 VGPRs (MFMA A/B frag)
typedef __attribute__((ext_vector_type(4))) float floatx4;  // MFMA C/D frag

#define MFMA16(a, b, c) __builtin_amdgcn_mfma_f32_16x16x32_bf16((a), (b), (c), 0, 0, 0)

// async global->LDS, 16B per lane (used only in the projection GEMMs)
__device__ __forceinline__ void gload_lds16(const void* g, void* lds) {
  __builtin_amdgcn_global_load_lds(
      (__attribute__((address_space(1))) void*)(void*)g,
      (__attribute__((address_space(3))) void*)lds, 16, 0, 0);
}

__device__ __forceinline__ unsigned short f2bf(float f) {
  union { float f; unsigned int u; } v;
  v.f = f;
  unsigned int r = v.u + 0x7fffu + ((v.u >> 16) & 1u);
  return (unsigned short)(r >> 16);
}
__device__ __forceinline__ float bf2f(unsigned short u) {
  union { unsigned int u; float f; } v;
  v.u = (unsigned int)u << 16;
  return v.f;
}

// ---------------- cast fp32 -> bf16, vectorized x4 ----------------
__global__ void cast_f32_bf16(const float* __restrict__ in, unsigned short* __restrict__ out, int n4) {
  int i = blockIdx.x * 256 + threadIdx.x;
  if (i < n4) {
    float4 f = ((const float4*)in)[i];
    uint2 p;
    p.x = (unsigned int)f2bf(f.x) | ((unsigned int)f2bf(f.y) << 16);
    p.y = (unsigned int)f2bf(f.z) | ((unsigned int)f2bf(f.w) << 16);
    ((uint2*)out)[i] = p;
  }
}

// Fragment-ordered layouts (16x16x32 MFMA operand fragments; one frag = 16 rows x
// 32 k x bf16 = 512 elems = 64 lane-ordered 16B chunks; chunk L = row(L&15),
// k = (L>>4)*8..+7). Reader: ds/global _b128 at base + lane*16 -> conflict-free.
//
// Qf/Kf per (b,h): frag(sblk = s>>4, ks = dk>>5):  idx = sblk*2 + ks   (128 B/frag-unit = 64 short8)
// Vf    per (b,h): frag(kblk = key>>5, db = dk>>4): idx = kblk*4 + db  (rows = dk)

// ---------------- GEMM: C[M=4096][N=1024] = A[M][K=1024] * W[N][K]^T ----------------
// m97-style: 128x128 tile, BK=32, 4 waves each 64x64.
// MODE 0: bf16 -> fragment-ordered Qf/Kf layout
// MODE 1: bf16 -> fragment-ordered Vf layout (rows = dk, k = key)
// MODE 2: fp32 row-major [token][e] (output projection)
template <int MODE>
__launch_bounds__(256, 2)
__global__ void gemm_bt(const unsigned short* __restrict__ A,
                        const unsigned short* __restrict__ Bw,
                        void* __restrict__ Out) {
  __shared__ unsigned short lA[128 * 32];
  __shared__ unsigned short lB[128 * 32];
  const int tid  = threadIdx.x;
  const int lane = tid & 63;
  const int wave = tid >> 6;
  const int m0 = blockIdx.y * 128;
  const int n0 = blockIdx.x * 128;
  const int K  = D_;
  const int wm = (wave >> 1) * 64;
  const int wn = (wave & 1) * 64;

  floatx4 acc[4][4] = {};

  for (int k0 = 0; k0 < K; k0 += 32) {
#pragma unroll
    for (int l = 0; l < 2; ++l) {
      int c = l * 256 + tid;
      int row = c >> 2, cb = (c & 3) * 16;
      const char* ga = (const char*)A + ((size_t)(m0 + row) * K + k0) * 2 + cb;
      gload_lds16(ga, (char*)lA + (size_t)(l * 256 + wave * 64) * 16);
      const char* gb = (const char*)Bw + ((size_t)(n0 + row) * K + k0) * 2 + cb;
      gload_lds16(gb, (char*)lB + (size_t)(l * 256 + wave * 64) * 16);
    }
    __syncthreads();

    short8 af[4], bf_[4];
#pragma unroll
    for (int mt = 0; mt < 4; ++mt)
      af[mt] = *(const short8*)&lA[(wm + mt * 16 + (lane & 15)) * 32 + (lane >> 4) * 8];
#pragma unroll
    for (int nt = 0; nt < 4; ++nt)
      bf_[nt] = *(const short8*)&lB[(wn + nt * 16 + (lane & 15)) * 32 + (lane >> 4) * 8];
#pragma unroll
    for (int mt = 0; mt < 4; ++mt)
#pragma unroll
      for (int nt = 0; nt < 4; ++nt)
        acc[mt][nt] = MFMA16(af[mt], bf_[nt], acc[mt][nt]);
    __syncthreads();
  }

  // epilogue — C/D layout: col = lane&15, row = (lane>>4)*4 + reg
  if (MODE == 0) {
    unsigned short* O = (unsigned short*)Out;
#pragma unroll
    for (int mt = 0; mt < 4; ++mt)
#pragma unroll
      for (int nt = 0; nt < 4; ++nt)
#pragma unroll
        for (int r = 0; r < 4; ++r) {
          int row = m0 + wm + mt * 16 + (lane >> 4) * 4 + r;  // token
          int col = n0 + wn + nt * 16 + (lane & 15);          // e
          int b = row >> 11, s = row & (S_ - 1);
          int h = col >> 6,  dk = col & 63;
          size_t base = (size_t)(b * H_ + h) * PERHEAD;
          int frag = (s >> 4) * 2 + (dk >> 5);
          int lp = (s & 15) | (((dk >> 3) & 3) << 4);
          O[base + (size_t)frag * 512 + lp * 8 + (dk & 7)] = f2bf(acc[mt][nt][r]);
        }
  } else if (MODE == 1) {
    unsigned short* O = (unsigned short*)Out;
#pragma unroll
    for (int mt = 0; mt < 4; ++mt)
#pragma unroll
      for (int nt = 0; nt < 4; ++nt) {
        int row0 = m0 + wm + mt * 16 + (lane >> 4) * 4;  // 4 consecutive tokens (keys)
        int col  = n0 + wn + nt * 16 + (lane & 15);
        int b = row0 >> 11, key0 = row0 & (S_ - 1);
        int h = col >> 6,   dk = col & 63;
        size_t base = (size_t)(b * H_ + h) * PERHEAD;
        int frag = (key0 >> 5) * 4 + (dk >> 4);
        int lp = (dk & 15) | (((key0 >> 3) & 3) << 4);
        unsigned long long pk =
            (unsigned long long)f2bf(acc[mt][nt][0]) |
            ((unsigned long long)f2bf(acc[mt][nt][1]) << 16) |
            ((unsigned long long)f2bf(acc[mt][nt][2]) << 32) |
            ((unsigned long long)f2bf(acc[mt][nt][3]) << 48);
        *(unsigned long long*)&O[base + (size_t)frag * 512 + lp * 8 + (key0 & 7)] = pk;
      }
  } else {
    float* O = (float*)Out;
#pragma unroll
    for (int mt = 0; mt < 4; ++mt)
#pragma unroll
      for (int nt = 0; nt < 4; ++nt)
#pragma unroll
        for (int r = 0; r < 4; ++r) {
          int row = m0 + wm + mt * 16 + (lane >> 4) * 4 + r;
          int col = n0 + wn + nt * 16 + (lane & 15);
          O[(size_t)row * D_ + col] = acc[mt][nt][r];
        }
  }
}

// ---------------- Pass 1: Zr[b,q,k] = bf16( 1 / sum_h exp(s/8) ) ----------------
// No LDS, no barriers: fragments load directly global->VGPR (coalesced: lane*16).
// Wave w owns q rows [q0 + w*16). Scores tiny (|s|<~3) -> exp w/o max-sub is safe.
__launch_bounds__(256, 4)
__global__ void compute_z(const unsigned short* __restrict__ Qf,
                          const unsigned short* __restrict__ Kf,
                          unsigned short* __restrict__ Zr) {
  const int tid = threadIdx.x, lane = tid & 63, wave = tid >> 6;
  const int k0 = blockIdx.x * 64, q0 = blockIdx.y * 64, b = blockIdx.z;

  floatx4 zacc[4] = {};
  const short8* qp = (const short8*)Qf + (size_t)b * H_ * (PERHEAD / 8)
                     + ((q0 >> 4) + wave) * 128 + lane;            // frag = sblk*2 -> *128 short8
  const short8* kp = (const short8*)Kf + (size_t)b * H_ * (PERHEAD / 8)
                     + (k0 >> 4) * 128 + lane;

#pragma unroll 1
  for (int h = 0; h < H_; ++h) {
    short8 aq0 = qp[0], aq1 = qp[64];
    floatx4 sacc[4] = {};
#pragma unroll
    for (int kb = 0; kb < 4; ++kb) {
      short8 b0 = kp[kb * 128];
      short8 b1 = kp[kb * 128 + 64];
      sacc[kb] = MFMA16(aq0, b0, sacc[kb]);
      sacc[kb] = MFMA16(aq1, b1, sacc[kb]);
    }
#pragma unroll
    for (int kb = 0; kb < 4; ++kb)
#pragma unroll
      for (int r = 0; r < 4; ++r)
        zacc[kb][r] += __expf(sacc[kb][r] * 0.125f);
    qp += PERHEAD / 8;
    kp += PERHEAD / 8;
  }

#pragma unroll
  for (int kb = 0; kb < 4; ++kb)
#pragma unroll
    for (int r = 0; r < 4; ++r) {
      int q = q0 + wave * 16 + (lane >> 4) * 4 + r;
      int k = k0 + kb * 16 + (lane & 15);
      Zr[((size_t)b * S_ + q) * S_ + k] = f2bf(1.0f / zacc[kb][r]);
    }
}

// ---------------- Pass 2: x^T = (exp(QK^T/8) .* Zr) @ V ----------------
// Block = (q-tile 64, h, b). S computed TRANSPOSED (m=key, n=q) so each lane exits
// QK holding 4 consecutive keys at one q -> single 8B write per qblk into a
// fragment-ordered P buffer; PV then reads P conflict-free (base + lane*16).
// All global operands (Qf,Kf,Vf,Zr) load direct to VGPRs; P double-buffered ->
// exactly ONE __syncthreads per k-tile.
__launch_bounds__(256, 4)
__global__ void attn_pv(const unsigned short* __restrict__ Qf,
                        const unsigned short* __restrict__ Kf,
                        const unsigned short* __restrict__ Vf,
                        const unsigned short* __restrict__ Zr,
                        unsigned short* __restrict__ X) {
  __shared__ unsigned short lP[2 * 4096];  // 2 x (64q x 64k) fragment-ordered; reused as lX
  const int tid = threadIdx.x, lane = tid & 63, wave = tid >> 6;
  const int h = blockIdx.x, b = blockIdx.z;
  const int q0 = blockIdx.y * 64;

  const size_t headf = (size_t)(b * H_ + h) * (PERHEAD / 8);  // short8 units
  // Q fragments for this q-tile: held in registers for the whole kernel
  short8 qf[4][2];
#pragma unroll
  for (int qb = 0; qb < 4; ++qb) {
    const short8* qp = (const short8*)Qf + headf + ((q0 >> 4) + qb) * 128 + lane;
    qf[qb][0] = qp[0];
    qf[qb][1] = qp[64];
  }
  const short8* kp = (const short8*)Kf + headf + wave * 128 + lane;       // sblk=wave; += 512/iter
  const short8* vp = (const short8*)Vf + headf + wave * 64 + lane;        // db=wave;  += 512/iter
  // FIX: include the lane's own q row (lane&15) — S^T orientation: n = q = qb*16 + (lane&15)
  const unsigned short* zp = Zr + ((size_t)b * S_ + q0 + (lane & 15)) * S_
                             + wave * 16 + ((lane >> 4) << 2);

  // P write address (ushort units, within buffer): fragment-ordered.
  // Lane holds 4 consecutive keys (wave*16 + (lane>>4)*4 + r) at q = qb*16 + (lane&15).
  const int pw_off = ((wave >> 1) << 9) + (((lane & 15) | (((wave & 1) << 1 | ((lane >> 4) >> 1)) << 4)) << 3)
                     + (((lane >> 4) & 1) << 2);

  floatx4 xacc[4] = {};  // x^T[dk = wave*16 + row][q = qb*16 + col]

  for (int kt = 0; kt < S_ / 64; ++kt) {
    const int buf = (kt & 1) << 12;
    // global fragment loads (independent; compiler schedules across barrier)
    short8 kf0 = kp[0], kf1 = kp[64];
    short8 vf0 = vp[0], vf1 = vp[256];
    uint2 zz[4];
#pragma unroll
    for (int qb = 0; qb < 4; ++qb)
      zz[qb] = *(const uint2*)(zp + (size_t)(qb * 16) * S_);

    // S^T tiles: m = 16 keys (wave's), n = 64 q
    floatx4 sacc[4] = {};
#pragma unroll
    for (int qb = 0; qb < 4; ++qb) {
      sacc[qb] = MFMA16(kf0, qf[qb][0], sacc[qb]);
      sacc[qb] = MFMA16(kf1, qf[qb][1], sacc[qb]);
    }
    // P = exp(s/8) * (1/Z) -> bf16, fragment-ordered in LDS
#pragma unroll
    for (int qb = 0; qb < 4; ++qb) {
      float z0 = bf2f((unsigned short)(zz[qb].x & 0xffff));
      float z1 = bf2f((unsigned short)(zz[qb].x >> 16));
      float z2 = bf2f((unsigned short)(zz[qb].y & 0xffff));
      float z3 = bf2f((unsigned short)(zz[qb].y >> 16));
      float e0 = __expf(sacc[qb][0] * 0.125f) * z0;
      float e1 = __expf(sacc[qb][1] * 0.125f) * z1;
      float e2 = __expf(sacc[qb][2] * 0.125f) * z2;
      float e3 = __expf(sacc[qb][3] * 0.125f) * z3;
      uint2 p;
      p.x = (unsigned int)f2bf(e0) | ((unsigned int)f2bf(e1) << 16);
      p.y = (unsigned int)f2bf(e2) | ((unsigned int)f2bf(e3) << 16);
      *(uint2*)&lP[buf + (qb << 10) + pw_off] = p;
    }
    __syncthreads();

    // x^T += V_frag @ P   (A: m=dk rows of Vf; B: P fragments, conflict-free reads)
#pragma unroll
    for (int qb = 0; qb < 4; ++qb) {
      short8 p0 = *(const short8*)&lP[buf + (qb << 10) + (lane << 3)];
      short8 p1 = *(const short8*)&lP[buf + (qb << 10) + 512 + (lane << 3)];
      xacc[qb] = MFMA16(vf0, p0, xacc[qb]);
      xacc[qb] = MFMA16(vf1, p1, xacc[qb]);
    }

    kp += 512;  // FIX: 64 keys = 4 sblks x 2 frags x 64 short8 = 512 (was 256)
    vp += 512;  // 2 kblks x 4 frags x 64 short8
    zp += 64;
  }

  // epilogue: transpose x^T -> x via padded LDS, then coalesced 16B stores
  __syncthreads();
  unsigned short* lX = lP;  // 64 rows(q) x 72 (dk padded)
#pragma unroll
  for (int qb = 0; qb < 4; ++qb)
#pragma unroll
    for (int r = 0; r < 4; ++r) {
      int q  = qb * 16 + (lane & 15);
      int dk = wave * 16 + (lane >> 4) * 4 + r;
      lX[q * 72 + dk] = f2bf(xacc[qb][r]);
    }
  __syncthreads();
  {
    int q = tid >> 2, cg = (tid & 3) * 16;
    short8 v0 = *(const short8*)&lX[q * 72 + cg];
    short8 v1 = *(const short8*)&lX[q * 72 + cg + 8];
    unsigned short* o = X + (size_t)(b * S_ + q0 + q) * D_ + h * DK_ + cg;
    *(short8*)&o[0] = v0;
    *(short8*)&o[8] = v1;
  }
}

// ---------------- launch ----------------
extern "C" void kernel_launch(void* const* d_in, const int* in_sizes, int n_in,
                              void* d_out, int out_size, void* d_ws, size_t ws_size,
                              hipStream_t stream) {
  const float* qi = (const float*)d_in[0];
  const float* ki = (const float*)d_in[1];
  const float* vi = (const float*)d_in[2];
  // d_in[3] = mask: reference discards masked_fill result -> unused
  const float* Wq = (const float*)d_in[4];
  const float* Wk = (const float*)d_in[5];
  const float* Wv = (const float*)d_in[6];
  const float* Wo = (const float*)d_in[7];

  const size_t NT = (size_t)B_ * S_ * D_;  // 4,194,304
  const size_t NW = (size_t)D_ * D_;       // 1,048,576

  unsigned short* w = (unsigned short*)d_ws;
  unsigned short* qi_bf = w; w += NT;
  unsigned short* ki_bf = w; w += NT;
  unsigned short* vi_bf = w; w += NT;
  unsigned short* Wq_bf = w; w += NW;
  unsigned short* Wk_bf = w; w += NW;
  unsigned short* Wv_bf = w; w += NW;
  unsigned short* Wo_bf = w; w += NW;
  unsigned short* Qf = w; w += NT;  // fragment-ordered per (b,h)
  unsigned short* Kf = w; w += NT;
  unsigned short* Vf = w; w += NT;
  unsigned short* Xb = w; w += NT;  // [b,s,e] row-major bf16
  unsigned short* Zr = w;           // [b,q,k] bf16, 16 MiB

  {
    int n4 = (int)(NT / 4);
    int g = (n4 + 255) / 256;
    cast_f32_bf16<<<g, 256, 0, stream>>>(qi, qi_bf, n4);
    cast_f32_bf16<<<g, 256, 0, stream>>>(ki, ki_bf, n4);
    cast_f32_bf16<<<g, 256, 0, stream>>>(vi, vi_bf, n4);
    int n4w = (int)(NW / 4);
    int gw = (n4w + 255) / 256;
    cast_f32_bf16<<<gw, 256, 0, stream>>>(Wq, Wq_bf, n4w);
    cast_f32_bf16<<<gw, 256, 0, stream>>>(Wk, Wk_bf, n4w);
    cast_f32_bf16<<<gw, 256, 0, stream>>>(Wv, Wv_bf, n4w);
    cast_f32_bf16<<<gw, 256, 0, stream>>>(Wo, Wo_bf, n4w);
  }

  dim3 gg(D_ / 128, (B_ * S_) / 128);  // (8, 32)
  gemm_bt<0><<<gg, 256, 0, stream>>>(qi_bf, Wq_bf, Qf);
  gemm_bt<0><<<gg, 256, 0, stream>>>(ki_bf, Wk_bf, Kf);
  gemm_bt<1><<<gg, 256, 0, stream>>>(vi_bf, Wv_bf, Vf);

  compute_z<<<dim3(S_ / 64, S_ / 64, B_), 256, 0, stream>>>(Qf, Kf, Zr);
  attn_pv<<<dim3(H_, S_ / 64, B_), 256, 0, stream>>>(Qf, Kf, Vf, Zr, Xb);

  gemm_bt<2><<<gg, 256, 0, stream>>>(Xb, Wo_bf, d_out);
}

// Round 4
// 319.268 us; speedup vs baseline: 1.1718x; 1.1057x over previous
//
#include <hip/hip_runtime.h>
#include <stdint.h>

// Problem constants (reference: B=2, S=2048, D=1024, H=16, DK=64)
#define B_  2
#define S_  2048
#define D_  1024
#define H_  16
#define DK_ 64
#define PERHEAD (S_ * DK_)  // 131072 elems per (b,h)

// exp(x*0.125) = exp2(x * 0.125*log2(e))
#define EXP2SCALE 0.18033688011112042f

typedef __attribute__((ext_vector_type(8))) short short8;   // 8 bf16 = 4 VGPRs (MFMA A/B frag)
typedef __attribute__((ext_vector_type(4))) float floatx4;  // MFMA C/D frag

#define MFMA16(a, b, c) __builtin_amdgcn_mfma_f32_16x16x32_bf16((a), (b), (c), 0, 0, 0)

// async global->LDS, 16B per lane (used only in the projection GEMMs)
__device__ __forceinline__ void gload_lds16(const void* g, void* lds) {
  __builtin_amdgcn_global_load_lds(
      (__attribute__((address_space(1))) void*)(void*)g,
      (__attribute__((address_space(3))) void*)lds, 16, 0, 0);
}

__device__ __forceinline__ unsigned short f2bf(float f) {
  union { float f; unsigned int u; } v;
  v.f = f;
  unsigned int r = v.u + 0x7fffu + ((v.u >> 16) & 1u);
  return (unsigned short)(r >> 16);
}
__device__ __forceinline__ float bf2f(unsigned short u) {
  union { unsigned int u; float f; } v;
  v.u = (unsigned int)u << 16;
  return v.f;
}

// ---------------- batched casts fp32 -> bf16 (one launch for 3 inputs / 4 weights) ----
__global__ void cast3_f32_bf16(const float* __restrict__ a0, const float* __restrict__ a1,
                               const float* __restrict__ a2,
                               unsigned short* __restrict__ o0, unsigned short* __restrict__ o1,
                               unsigned short* __restrict__ o2, int n4) {
  const float* in = (blockIdx.z == 0) ? a0 : (blockIdx.z == 1) ? a1 : a2;
  unsigned short* out = (blockIdx.z == 0) ? o0 : (blockIdx.z == 1) ? o1 : o2;
  int i = blockIdx.x * 256 + threadIdx.x;
  if (i < n4) {
    float4 f = ((const float4*)in)[i];
    uint2 p;
    p.x = (unsigned int)f2bf(f.x) | ((unsigned int)f2bf(f.y) << 16);
    p.y = (unsigned int)f2bf(f.z) | ((unsigned int)f2bf(f.w) << 16);
    ((uint2*)out)[i] = p;
  }
}
__global__ void cast4_f32_bf16(const float* __restrict__ a0, const float* __restrict__ a1,
                               const float* __restrict__ a2, const float* __restrict__ a3,
                               unsigned short* __restrict__ o0, unsigned short* __restrict__ o1,
                               unsigned short* __restrict__ o2, unsigned short* __restrict__ o3,
                               int n4) {
  const float* in = (blockIdx.z == 0) ? a0 : (blockIdx.z == 1) ? a1 : (blockIdx.z == 2) ? a2 : a3;
  unsigned short* out = (blockIdx.z == 0) ? o0 : (blockIdx.z == 1) ? o1 : (blockIdx.z == 2) ? o2 : o3;
  int i = blockIdx.x * 256 + threadIdx.x;
  if (i < n4) {
    float4 f = ((const float4*)in)[i];
    uint2 p;
    p.x = (unsigned int)f2bf(f.x) | ((unsigned int)f2bf(f.y) << 16);
    p.y = (unsigned int)f2bf(f.z) | ((unsigned int)f2bf(f.w) << 16);
    ((uint2*)out)[i] = p;
  }
}

// Fragment-ordered layouts (16x16x32 MFMA operand fragments; one frag = 16 rows x
// 32 k x bf16 = 512 elems = 64 lane-ordered 16B chunks; chunk L = row(L&15),
// k = (L>>4)*8..+7). Reader: ds/global _b128 at base + lane*16 -> conflict-free.
//
// Qf/Kf per (b,h): frag(sblk = s>>4, ks = dk>>5):  idx = sblk*2 + ks
// Vf    per (b,h): frag(kblk = key>>5, db = dk>>4): idx = kblk*4 + db  (rows = dk)

// ---------------- shared GEMM core: 128x128 tile, BK=32, 4 waves each 64x64 ----------
__device__ __forceinline__ void gemm_core(const unsigned short* __restrict__ A,
                                          const unsigned short* __restrict__ Bw,
                                          unsigned short* lA, unsigned short* lB,
                                          int m0, int n0, int tid, int lane, int wave,
                                          floatx4 acc[4][4]) {
  const int wm = (wave >> 1) * 64;
  const int wn = (wave & 1) * 64;
  for (int k0 = 0; k0 < D_; k0 += 32) {
#pragma unroll
    for (int l = 0; l < 2; ++l) {
      int c = l * 256 + tid;
      int row = c >> 2, cb = (c & 3) * 16;
      const char* ga = (const char*)A + ((size_t)(m0 + row) * D_ + k0) * 2 + cb;
      gload_lds16(ga, (char*)lA + (size_t)(l * 256 + wave * 64) * 16);
      const char* gb = (const char*)Bw + ((size_t)(n0 + row) * D_ + k0) * 2 + cb;
      gload_lds16(gb, (char*)lB + (size_t)(l * 256 + wave * 64) * 16);
    }
    __syncthreads();
    short8 af[4], bf_[4];
#pragma unroll
    for (int mt = 0; mt < 4; ++mt)
      af[mt] = *(const short8*)&lA[(wm + mt * 16 + (lane & 15)) * 32 + (lane >> 4) * 8];
#pragma unroll
    for (int nt = 0; nt < 4; ++nt)
      bf_[nt] = *(const short8*)&lB[(wn + nt * 16 + (lane & 15)) * 32 + (lane >> 4) * 8];
#pragma unroll
    for (int mt = 0; mt < 4; ++mt)
#pragma unroll
      for (int nt = 0; nt < 4; ++nt)
        acc[mt][nt] = MFMA16(af[mt], bf_[nt], acc[mt][nt]);
    __syncthreads();
  }
}

// ---------------- fused QKV projection: z selects (A, W, Out, epilogue) ----------------
__launch_bounds__(256, 2)
__global__ void gemm_qkv(const unsigned short* __restrict__ qi, const unsigned short* __restrict__ ki,
                         const unsigned short* __restrict__ vi,
                         const unsigned short* __restrict__ Wq, const unsigned short* __restrict__ Wk,
                         const unsigned short* __restrict__ Wv,
                         unsigned short* __restrict__ Qf, unsigned short* __restrict__ Kf,
                         unsigned short* __restrict__ Vf) {
  __shared__ unsigned short lA[128 * 32];
  __shared__ unsigned short lB[128 * 32];
  const int z = blockIdx.z;
  const unsigned short* A  = (z == 0) ? qi : (z == 1) ? ki : vi;
  const unsigned short* Bw = (z == 0) ? Wq : (z == 1) ? Wk : Wv;
  unsigned short* O        = (z == 0) ? Qf : (z == 1) ? Kf : Vf;
  const int tid = threadIdx.x, lane = tid & 63, wave = tid >> 6;
  const int m0 = blockIdx.y * 128, n0 = blockIdx.x * 128;
  const int wm = (wave >> 1) * 64, wn = (wave & 1) * 64;

  floatx4 acc[4][4] = {};
  gemm_core(A, Bw, lA, lB, m0, n0, tid, lane, wave, acc);

  if (z < 2) {  // Qf/Kf fragment layout
#pragma unroll
    for (int mt = 0; mt < 4; ++mt)
#pragma unroll
      for (int nt = 0; nt < 4; ++nt)
#pragma unroll
        for (int r = 0; r < 4; ++r) {
          int row = m0 + wm + mt * 16 + (lane >> 4) * 4 + r;  // token
          int col = n0 + wn + nt * 16 + (lane & 15);          // e
          int b = row >> 11, s = row & (S_ - 1);
          int h = col >> 6,  dk = col & 63;
          size_t base = (size_t)(b * H_ + h) * PERHEAD;
          int frag = (s >> 4) * 2 + (dk >> 5);
          int lp = (s & 15) | (((dk >> 3) & 3) << 4);
          O[base + (size_t)frag * 512 + lp * 8 + (dk & 7)] = f2bf(acc[mt][nt][r]);
        }
  } else {  // Vf fragment layout (rows = dk, k = key)
#pragma unroll
    for (int mt = 0; mt < 4; ++mt)
#pragma unroll
      for (int nt = 0; nt < 4; ++nt) {
        int row0 = m0 + wm + mt * 16 + (lane >> 4) * 4;  // 4 consecutive keys
        int col  = n0 + wn + nt * 16 + (lane & 15);
        int b = row0 >> 11, key0 = row0 & (S_ - 1);
        int h = col >> 6,   dk = col & 63;
        size_t base = (size_t)(b * H_ + h) * PERHEAD;
        int frag = (key0 >> 5) * 4 + (dk >> 4);
        int lp = (dk & 15) | (((key0 >> 3) & 3) << 4);
        unsigned long long pk =
            (unsigned long long)f2bf(acc[mt][nt][0]) |
            ((unsigned long long)f2bf(acc[mt][nt][1]) << 16) |
            ((unsigned long long)f2bf(acc[mt][nt][2]) << 32) |
            ((unsigned long long)f2bf(acc[mt][nt][3]) << 48);
        *(unsigned long long*)&O[base + (size_t)frag * 512 + lp * 8 + (key0 & 7)] = pk;
      }
  }
}

// ---------------- output projection: fp32 row-major ----------------
__launch_bounds__(256, 2)
__global__ void gemm_out(const unsigned short* __restrict__ A, const unsigned short* __restrict__ Bw,
                         float* __restrict__ O) {
  __shared__ unsigned short lA[128 * 32];
  __shared__ unsigned short lB[128 * 32];
  const int tid = threadIdx.x, lane = tid & 63, wave = tid >> 6;
  const int m0 = blockIdx.y * 128, n0 = blockIdx.x * 128;
  const int wm = (wave >> 1) * 64, wn = (wave & 1) * 64;
  floatx4 acc[4][4] = {};
  gemm_core(A, Bw, lA, lB, m0, n0, tid, lane, wave, acc);
#pragma unroll
  for (int mt = 0; mt < 4; ++mt)
#pragma unroll
    for (int nt = 0; nt < 4; ++nt)
#pragma unroll
      for (int r = 0; r < 4; ++r) {
        int row = m0 + wm + mt * 16 + (lane >> 4) * 4 + r;
        int col = n0 + wn + nt * 16 + (lane & 15);
        O[(size_t)row * D_ + col] = acc[mt][nt][r];
      }
}

// ---------------- Pass 1: Zr[b,q,k] = bf16( 1 / sum_h exp(s/8) ) ----------------
// No LDS, no barriers. unroll 2 on heads: next head's 10 fragment loads issue while
// the current head's MFMA+exp chain executes (pure latency-bound loop otherwise).
__launch_bounds__(256, 4)
__global__ void compute_z(const unsigned short* __restrict__ Qf,
                          const unsigned short* __restrict__ Kf,
                          unsigned short* __restrict__ Zr) {
  const int tid = threadIdx.x, lane = tid & 63, wave = tid >> 6;
  const int k0 = blockIdx.x * 64, q0 = blockIdx.y * 64, b = blockIdx.z;

  floatx4 zacc[4] = {};
  const short8* qp = (const short8*)Qf + (size_t)b * H_ * (PERHEAD / 8)
                     + ((q0 >> 4) + wave) * 128 + lane;
  const short8* kp = (const short8*)Kf + (size_t)b * H_ * (PERHEAD / 8)
                     + (k0 >> 4) * 128 + lane;

#pragma unroll 2
  for (int h = 0; h < H_; ++h) {
    short8 aq0 = qp[0], aq1 = qp[64];
    floatx4 sacc[4] = {};
#pragma unroll
    for (int kb = 0; kb < 4; ++kb) {
      short8 b0 = kp[kb * 128];
      short8 b1 = kp[kb * 128 + 64];
      sacc[kb] = MFMA16(aq0, b0, sacc[kb]);
      sacc[kb] = MFMA16(aq1, b1, sacc[kb]);
    }
#pragma unroll
    for (int kb = 0; kb < 4; ++kb)
#pragma unroll
      for (int r = 0; r < 4; ++r)
        zacc[kb][r] += exp2f(sacc[kb][r] * EXP2SCALE);
    qp += PERHEAD / 8;
    kp += PERHEAD / 8;
  }

#pragma unroll
  for (int kb = 0; kb < 4; ++kb)
#pragma unroll
    for (int r = 0; r < 4; ++r) {
      int q = q0 + wave * 16 + (lane >> 4) * 4 + r;
      int k = k0 + kb * 16 + (lane & 15);
      Zr[((size_t)b * S_ + q) * S_ + k] = f2bf(1.0f / zacc[kb][r]);
    }
}

// ---------------- Pass 2: x^T = (exp(QK^T/8) .* Zr) @ V ----------------
// Block = (q-tile 64, h, b). S computed TRANSPOSED (m=key, n=q). TWO 64-key tiles
// per barrier epoch (128 keys): halves barrier count, doubles independent work per
// epoch for latency overlap. P double-buffered (2 tiles x 8KB x 2 bufs = 32 KB LDS).
__launch_bounds__(256, 3)
__global__ void attn_pv(const unsigned short* __restrict__ Qf,
                        const unsigned short* __restrict__ Kf,
                        const unsigned short* __restrict__ Vf,
                        const unsigned short* __restrict__ Zr,
                        unsigned short* __restrict__ X) {
  __shared__ unsigned short lP[2 * 8192];  // 2 bufs x 2 tiles x 4096 ushort
  const int tid = threadIdx.x, lane = tid & 63, wave = tid >> 6;
  const int h = blockIdx.x, b = blockIdx.z;
  const int q0 = blockIdx.y * 64;

  const size_t headf = (size_t)(b * H_ + h) * (PERHEAD / 8);  // short8 units
  short8 qf[4][2];
#pragma unroll
  for (int qb = 0; qb < 4; ++qb) {
    const short8* qp = (const short8*)Qf + headf + ((q0 >> 4) + qb) * 128 + lane;
    qf[qb][0] = qp[0];
    qf[qb][1] = qp[64];
  }
  const short8* kp = (const short8*)Kf + headf + wave * 128 + lane;  // += 1024/epoch
  const short8* vp = (const short8*)Vf + headf + wave * 64 + lane;   // += 1024/epoch
  const unsigned short* zp = Zr + ((size_t)b * S_ + q0 + (lane & 15)) * S_
                             + wave * 16 + ((lane >> 4) << 2);

  // P write offset within a 4096-ushort tile region (fragment-ordered)
  const int pw_off = ((wave >> 1) << 9)
                   + (((lane & 15) | (((wave & 1) << 1 | ((lane >> 4) >> 1)) << 4)) << 3)
                   + (((lane >> 4) & 1) << 2);

  floatx4 xacc[4] = {};  // x^T[dk = wave*16 + row][q = qb*16 + col]

  for (int kt2 = 0; kt2 < S_ / 128; ++kt2) {
    const int buf = (kt2 & 1) << 13;  // 8192 ushort per buffer
    // global fragment loads for BOTH tiles (independent -> deep in flight)
    short8 kA0 = kp[0],   kA1 = kp[64];
    short8 kB0 = kp[512], kB1 = kp[576];
    short8 vA0 = vp[0],   vA1 = vp[256];
    short8 vB0 = vp[512], vB1 = vp[768];
    uint2 zzA[4], zzB[4];
#pragma unroll
    for (int qb = 0; qb < 4; ++qb) {
      zzA[qb] = *(const uint2*)(zp + (size_t)(qb * 16) * S_);
      zzB[qb] = *(const uint2*)(zp + (size_t)(qb * 16) * S_ + 64);
    }

    // tile A: S^T, exp, P -> lP[buf + 0]
    {
      floatx4 sacc[4] = {};
#pragma unroll
      for (int qb = 0; qb < 4; ++qb) {
        sacc[qb] = MFMA16(kA0, qf[qb][0], sacc[qb]);
        sacc[qb] = MFMA16(kA1, qf[qb][1], sacc[qb]);
      }
#pragma unroll
      for (int qb = 0; qb < 4; ++qb) {
        float e0 = exp2f(sacc[qb][0] * EXP2SCALE) * bf2f((unsigned short)(zzA[qb].x & 0xffff));
        float e1 = exp2f(sacc[qb][1] * EXP2SCALE) * bf2f((unsigned short)(zzA[qb].x >> 16));
        float e2 = exp2f(sacc[qb][2] * EXP2SCALE) * bf2f((unsigned short)(zzA[qb].y & 0xffff));
        float e3 = exp2f(sacc[qb][3] * EXP2SCALE) * bf2f((unsigned short)(zzA[qb].y >> 16));
        uint2 p;
        p.x = (unsigned int)f2bf(e0) | ((unsigned int)f2bf(e1) << 16);
        p.y = (unsigned int)f2bf(e2) | ((unsigned int)f2bf(e3) << 16);
        *(uint2*)&lP[buf + (qb << 10) + pw_off] = p;
      }
    }
    // tile B: S^T, exp, P -> lP[buf + 4096]
    {
      floatx4 sacc[4] = {};
#pragma unroll
      for (int qb = 0; qb < 4; ++qb) {
        sacc[qb] = MFMA16(kB0, qf[qb][0], sacc[qb]);
        sacc[qb] = MFMA16(kB1, qf[qb][1], sacc[qb]);
      }
#pragma unroll
      for (int qb = 0; qb < 4; ++qb) {
        float e0 = exp2f(sacc[qb][0] * EXP2SCALE) * bf2f((unsigned short)(zzB[qb].x & 0xffff));
        float e1 = exp2f(sacc[qb][1] * EXP2SCALE) * bf2f((unsigned short)(zzB[qb].x >> 16));
        float e2 = exp2f(sacc[qb][2] * EXP2SCALE) * bf2f((unsigned short)(zzB[qb].y & 0xffff));
        float e3 = exp2f(sacc[qb][3] * EXP2SCALE) * bf2f((unsigned short)(zzB[qb].y >> 16));
        uint2 p;
        p.x = (unsigned int)f2bf(e0) | ((unsigned int)f2bf(e1) << 16);
        p.y = (unsigned int)f2bf(e2) | ((unsigned int)f2bf(e3) << 16);
        *(uint2*)&lP[buf + 4096 + (qb << 10) + pw_off] = p;
      }
    }
    __syncthreads();

    // PV for both tiles
#pragma unroll
    for (int qb = 0; qb < 4; ++qb) {
      short8 pA0 = *(const short8*)&lP[buf + (qb << 10) + (lane << 3)];
      short8 pA1 = *(const short8*)&lP[buf + (qb << 10) + 512 + (lane << 3)];
      short8 pB0 = *(const short8*)&lP[buf + 4096 + (qb << 10) + (lane << 3)];
      short8 pB1 = *(const short8*)&lP[buf + 4096 + (qb << 10) + 512 + (lane << 3)];
      xacc[qb] = MFMA16(vA0, pA0, xacc[qb]);
      xacc[qb] = MFMA16(vA1, pA1, xacc[qb]);
      xacc[qb] = MFMA16(vB0, pB0, xacc[qb]);
      xacc[qb] = MFMA16(vB1, pB1, xacc[qb]);
    }

    kp += 1024;  // 128 keys = 8 sblks x 2 frags x 64 short8
    vp += 1024;  // 4 kblks x 4 frags x 64 short8
    zp += 128;
  }

  // epilogue: transpose x^T -> x via padded LDS, then coalesced 16B stores
  __syncthreads();
  unsigned short* lX = lP;  // 64 rows(q) x 72 (dk padded)
#pragma unroll
  for (int qb = 0; qb < 4; ++qb)
#pragma unroll
    for (int r = 0; r < 4; ++r) {
      int q  = qb * 16 + (lane & 15);
      int dk = wave * 16 + (lane >> 4) * 4 + r;
      lX[q * 72 + dk] = f2bf(xacc[qb][r]);
    }
  __syncthreads();
  {
    int q = tid >> 2, cg = (tid & 3) * 16;
    short8 v0 = *(const short8*)&lX[q * 72 + cg];
    short8 v1 = *(const short8*)&lX[q * 72 + cg + 8];
    unsigned short* o = X + (size_t)(b * S_ + q0 + q) * D_ + h * DK_ + cg;
    *(short8*)&o[0] = v0;
    *(short8*)&o[8] = v1;
  }
}

// ---------------- launch ----------------
extern "C" void kernel_launch(void* const* d_in, const int* in_sizes, int n_in,
                              void* d_out, int out_size, void* d_ws, size_t ws_size,
                              hipStream_t stream) {
  const float* qi = (const float*)d_in[0];
  const float* ki = (const float*)d_in[1];
  const float* vi = (const float*)d_in[2];
  // d_in[3] = mask: reference discards masked_fill result -> unused
  const float* Wq = (const float*)d_in[4];
  const float* Wk = (const float*)d_in[5];
  const float* Wv = (const float*)d_in[6];
  const float* Wo = (const float*)d_in[7];

  const size_t NT = (size_t)B_ * S_ * D_;  // 4,194,304
  const size_t NW = (size_t)D_ * D_;       // 1,048,576

  unsigned short* w = (unsigned short*)d_ws;
  unsigned short* qi_bf = w; w += NT;
  unsigned short* ki_bf = w; w += NT;
  unsigned short* vi_bf = w; w += NT;
  unsigned short* Wq_bf = w; w += NW;
  unsigned short* Wk_bf = w; w += NW;
  unsigned short* Wv_bf = w; w += NW;
  unsigned short* Wo_bf = w; w += NW;
  unsigned short* Qf = w; w += NT;  // fragment-ordered per (b,h)
  unsigned short* Kf = w; w += NT;
  unsigned short* Vf = w; w += NT;
  unsigned short* Xb = w; w += NT;  // [b,s,e] row-major bf16
  unsigned short* Zr = w;           // [b,q,k] bf16, 16 MiB

  {
    int n4 = (int)(NT / 4);   // 1048576 -> 4096 blocks
    cast3_f32_bf16<<<dim3((n4 + 255) / 256, 1, 3), 256, 0, stream>>>(
        qi, ki, vi, qi_bf, ki_bf, vi_bf, n4);
    int n4w = (int)(NW / 4);  // 262144 -> 1024 blocks
    cast4_f32_bf16<<<dim3((n4w + 255) / 256, 1, 4), 256, 0, stream>>>(
        Wq, Wk, Wv, Wo, Wq_bf, Wk_bf, Wv_bf, Wo_bf, n4w);
  }

  gemm_qkv<<<dim3(D_ / 128, (B_ * S_) / 128, 3), 256, 0, stream>>>(
      qi_bf, ki_bf, vi_bf, Wq_bf, Wk_bf, Wv_bf, Qf, Kf, Vf);

  compute_z<<<dim3(S_ / 64, S_ / 64, B_), 256, 0, stream>>>(Qf, Kf, Zr);
  attn_pv<<<dim3(H_, S_ / 64, B_), 256, 0, stream>>>(Qf, Kf, Vf, Zr, Xb);

  gemm_out<<<dim3(D_ / 128, (B_ * S_) / 128), 256, 0, stream>>>(Xb, Wo_bf, (float*)d_out);
}

// Round 5
// 318.810 us; speedup vs baseline: 1.1735x; 1.0014x over previous
//
#include <hip/hip_runtime.h>
#include <stdint.h>

// Problem constants (reference: B=2, S=2048, D=1024, H=16, DK=64)
#define B_  2
#define S_  2048
#define D_  1024
#define H_  16
#define DK_ 64
#define PERHEAD (S_ * DK_)  // 131072 elems per (b,h)

// exp(x*0.125) = exp2(x * 0.125*log2(e))
#define EXP2SCALE 0.18033688011112042f

typedef __attribute__((ext_vector_type(8))) short short8;   // 8 bf16 = 4 VGPRs (MFMA A/B frag)
typedef __attribute__((ext_vector_type(4))) float floatx4;  // MFMA C/D frag

#define MFMA16(a, b, c) __builtin_amdgcn_mfma_f32_16x16x32_bf16((a), (b), (c), 0, 0, 0)

// async global->LDS, 16B per lane (used only in the projection GEMMs)
__device__ __forceinline__ void gload_lds16(const void* g, void* lds) {
  __builtin_amdgcn_global_load_lds(
      (__attribute__((address_space(1))) void*)(void*)g,
      (__attribute__((address_space(3))) void*)lds, 16, 0, 0);
}

__device__ __forceinline__ unsigned short f2bf(float f) {
  union { float f; unsigned int u; } v;
  v.f = f;
  unsigned int r = v.u + 0x7fffu + ((v.u >> 16) & 1u);
  return (unsigned short)(r >> 16);
}

// pack two positive f32 into two bf16 (round-half-up: +0x8000 then take hi16 via v_perm)
__device__ __forceinline__ unsigned int pack_bf16_rhu(float e0, float e1) {
  unsigned int u0 = __float_as_uint(e0) + 0x8000u;
  unsigned int u1 = __float_as_uint(e1) + 0x8000u;
  return __builtin_amdgcn_perm(u1, u0, 0x07060302);  // {u1.hi16, u0.hi16}
}

// ---------------- batched casts fp32 -> bf16 (one launch for 3 inputs / 4 weights) ----
__global__ void cast3_f32_bf16(const float* __restrict__ a0, const float* __restrict__ a1,
                               const float* __restrict__ a2,
                               unsigned short* __restrict__ o0, unsigned short* __restrict__ o1,
                               unsigned short* __restrict__ o2, int n4) {
  const float* in = (blockIdx.z == 0) ? a0 : (blockIdx.z == 1) ? a1 : a2;
  unsigned short* out = (blockIdx.z == 0) ? o0 : (blockIdx.z == 1) ? o1 : o2;
  int i = blockIdx.x * 256 + threadIdx.x;
  if (i < n4) {
    float4 f = ((const float4*)in)[i];
    uint2 p;
    p.x = (unsigned int)f2bf(f.x) | ((unsigned int)f2bf(f.y) << 16);
    p.y = (unsigned int)f2bf(f.z) | ((unsigned int)f2bf(f.w) << 16);
    ((uint2*)out)[i] = p;
  }
}
__global__ void cast4_f32_bf16(const float* __restrict__ a0, const float* __restrict__ a1,
                               const float* __restrict__ a2, const float* __restrict__ a3,
                               unsigned short* __restrict__ o0, unsigned short* __restrict__ o1,
                               unsigned short* __restrict__ o2, unsigned short* __restrict__ o3,
                               int n4) {
  const float* in = (blockIdx.z == 0) ? a0 : (blockIdx.z == 1) ? a1 : (blockIdx.z == 2) ? a2 : a3;
  unsigned short* out = (blockIdx.z == 0) ? o0 : (blockIdx.z == 1) ? o1 : (blockIdx.z == 2) ? o2 : o3;
  int i = blockIdx.x * 256 + threadIdx.x;
  if (i < n4) {
    float4 f = ((const float4*)in)[i];
    uint2 p;
    p.x = (unsigned int)f2bf(f.x) | ((unsigned int)f2bf(f.y) << 16);
    p.y = (unsigned int)f2bf(f.z) | ((unsigned int)f2bf(f.w) << 16);
    ((uint2*)out)[i] = p;
  }
}

// Fragment-ordered layouts (16x16x32 MFMA operand fragments; one frag = 16 rows x
// 32 k x bf16 = 512 elems = 64 lane-ordered 16B chunks; chunk L = row(L&15),
// k = (L>>4)*8..+7). Reader: ds/global _b128 at base + lane*16 -> conflict-free.
//
// Qf/Kf per (b,h): frag(sblk = s>>4, ks = dk>>5):  idx = sblk*2 + ks
// Vf    per (b,h): frag(kblk = key>>5, db = dk>>4): idx = kblk*4 + db  (rows = dk)

// ---------------- shared GEMM core: 128x128 tile, BK=32, 4 waves each 64x64 ----------
__device__ __forceinline__ void gemm_core(const unsigned short* __restrict__ A,
                                          const unsigned short* __restrict__ Bw,
                                          unsigned short* lA, unsigned short* lB,
                                          int m0, int n0, int tid, int lane, int wave,
                                          floatx4 acc[4][4]) {
  const int wm = (wave >> 1) * 64;
  const int wn = (wave & 1) * 64;
  for (int k0 = 0; k0 < D_; k0 += 32) {
#pragma unroll
    for (int l = 0; l < 2; ++l) {
      int c = l * 256 + tid;
      int row = c >> 2, cb = (c & 3) * 16;
      const char* ga = (const char*)A + ((size_t)(m0 + row) * D_ + k0) * 2 + cb;
      gload_lds16(ga, (char*)lA + (size_t)(l * 256 + wave * 64) * 16);
      const char* gb = (const char*)Bw + ((size_t)(n0 + row) * D_ + k0) * 2 + cb;
      gload_lds16(gb, (char*)lB + (size_t)(l * 256 + wave * 64) * 16);
    }
    __syncthreads();
    short8 af[4], bf_[4];
#pragma unroll
    for (int mt = 0; mt < 4; ++mt)
      af[mt] = *(const short8*)&lA[(wm + mt * 16 + (lane & 15)) * 32 + (lane >> 4) * 8];
#pragma unroll
    for (int nt = 0; nt < 4; ++nt)
      bf_[nt] = *(const short8*)&lB[(wn + nt * 16 + (lane & 15)) * 32 + (lane >> 4) * 8];
#pragma unroll
    for (int mt = 0; mt < 4; ++mt)
#pragma unroll
      for (int nt = 0; nt < 4; ++nt)
        acc[mt][nt] = MFMA16(af[mt], bf_[nt], acc[mt][nt]);
    __syncthreads();
  }
}

// ---------------- fused QKV projection: z selects (A, W, Out, epilogue) ----------------
__launch_bounds__(256, 2)
__global__ void gemm_qkv(const unsigned short* __restrict__ qi, const unsigned short* __restrict__ ki,
                         const unsigned short* __restrict__ vi,
                         const unsigned short* __restrict__ Wq, const unsigned short* __restrict__ Wk,
                         const unsigned short* __restrict__ Wv,
                         unsigned short* __restrict__ Qf, unsigned short* __restrict__ Kf,
                         unsigned short* __restrict__ Vf) {
  __shared__ unsigned short lA[128 * 32];
  __shared__ unsigned short lB[128 * 32];
  const int z = blockIdx.z;
  const unsigned short* A  = (z == 0) ? qi : (z == 1) ? ki : vi;
  const unsigned short* Bw = (z == 0) ? Wq : (z == 1) ? Wk : Wv;
  unsigned short* O        = (z == 0) ? Qf : (z == 1) ? Kf : Vf;
  const int tid = threadIdx.x, lane = tid & 63, wave = tid >> 6;
  const int m0 = blockIdx.y * 128, n0 = blockIdx.x * 128;
  const int wm = (wave >> 1) * 64, wn = (wave & 1) * 64;

  floatx4 acc[4][4] = {};
  gemm_core(A, Bw, lA, lB, m0, n0, tid, lane, wave, acc);

  if (z < 2) {  // Qf/Kf fragment layout
#pragma unroll
    for (int mt = 0; mt < 4; ++mt)
#pragma unroll
      for (int nt = 0; nt < 4; ++nt)
#pragma unroll
        for (int r = 0; r < 4; ++r) {
          int row = m0 + wm + mt * 16 + (lane >> 4) * 4 + r;  // token
          int col = n0 + wn + nt * 16 + (lane & 15);          // e
          int b = row >> 11, s = row & (S_ - 1);
          int h = col >> 6,  dk = col & 63;
          size_t base = (size_t)(b * H_ + h) * PERHEAD;
          int frag = (s >> 4) * 2 + (dk >> 5);
          int lp = (s & 15) | (((dk >> 3) & 3) << 4);
          O[base + (size_t)frag * 512 + lp * 8 + (dk & 7)] = f2bf(acc[mt][nt][r]);
        }
  } else {  // Vf fragment layout (rows = dk, k = key)
#pragma unroll
    for (int mt = 0; mt < 4; ++mt)
#pragma unroll
      for (int nt = 0; nt < 4; ++nt) {
        int row0 = m0 + wm + mt * 16 + (lane >> 4) * 4;  // 4 consecutive keys
        int col  = n0 + wn + nt * 16 + (lane & 15);
        int b = row0 >> 11, key0 = row0 & (S_ - 1);
        int h = col >> 6,   dk = col & 63;
        size_t base = (size_t)(b * H_ + h) * PERHEAD;
        int frag = (key0 >> 5) * 4 + (dk >> 4);
        int lp = (dk & 15) | (((key0 >> 3) & 3) << 4);
        unsigned long long pk =
            (unsigned long long)f2bf(acc[mt][nt][0]) |
            ((unsigned long long)f2bf(acc[mt][nt][1]) << 16) |
            ((unsigned long long)f2bf(acc[mt][nt][2]) << 32) |
            ((unsigned long long)f2bf(acc[mt][nt][3]) << 48);
        *(unsigned long long*)&O[base + (size_t)frag * 512 + lp * 8 + (key0 & 7)] = pk;
      }
  }
}

// ---------------- output projection: fp32 row-major ----------------
__launch_bounds__(256, 2)
__global__ void gemm_out(const unsigned short* __restrict__ A, const unsigned short* __restrict__ Bw,
                         float* __restrict__ O) {
  __shared__ unsigned short lA[128 * 32];
  __shared__ unsigned short lB[128 * 32];
  const int tid = threadIdx.x, lane = tid & 63, wave = tid >> 6;
  const int m0 = blockIdx.y * 128, n0 = blockIdx.x * 128;
  const int wm = (wave >> 1) * 64, wn = (wave & 1) * 64;
  floatx4 acc[4][4] = {};
  gemm_core(A, Bw, lA, lB, m0, n0, tid, lane, wave, acc);
#pragma unroll
  for (int mt = 0; mt < 4; ++mt)
#pragma unroll
    for (int nt = 0; nt < 4; ++nt)
#pragma unroll
      for (int r = 0; r < 4; ++r) {
        int row = m0 + wm + mt * 16 + (lane >> 4) * 4 + r;
        int col = n0 + wn + nt * 16 + (lane & 15);
        O[(size_t)row * D_ + col] = acc[mt][nt][r];
      }
}

// ---------------- Pass 1: Zl[b,q,k] = fp16( log2( sum_h exp2(s*C) ) ) ----------------
// 128x128 tiles (grid 16x16x2): halves Q/K re-read traffic vs 64x64 (2 GB -> 1 GB
// L2/L3-side). No LDS, no barriers. Wave w owns q rows [q0+w*32, +32).
// K staged 4 frag-pairs at a time to keep VGPR ~130 (zacc 64 + kst 32 + qf 16).
__launch_bounds__(256, 3)
__global__ void compute_z(const unsigned short* __restrict__ Qf,
                          const unsigned short* __restrict__ Kf,
                          unsigned short* __restrict__ Zl) {
  const int tid = threadIdx.x, lane = tid & 63, wave = tid >> 6;
  const int k0 = blockIdx.x * 128, q0 = blockIdx.y * 128, b = blockIdx.z;

  floatx4 zacc[2][8] = {};
  const short8* qbase = (const short8*)Qf + (size_t)b * H_ * (PERHEAD / 8)
                        + ((q0 >> 4) + wave * 2) * 128 + lane;
  const short8* kbase = (const short8*)Kf + (size_t)b * H_ * (PERHEAD / 8)
                        + (k0 >> 4) * 128 + lane;

#pragma unroll 1
  for (int h = 0; h < H_; ++h) {
    short8 qf0 = qbase[0], qf1 = qbase[64];    // sq=0, ks=0/1
    short8 qf2 = qbase[128], qf3 = qbase[192]; // sq=1, ks=0/1
#pragma unroll
    for (int hf = 0; hf < 2; ++hf) {
      short8 kst[4][2];
#pragma unroll
      for (int kb = 0; kb < 4; ++kb) {
        kst[kb][0] = kbase[(hf * 4 + kb) * 128];
        kst[kb][1] = kbase[(hf * 4 + kb) * 128 + 64];
      }
#pragma unroll
      for (int kb = 0; kb < 4; ++kb) {
        floatx4 s0 = {}, s1 = {};
        s0 = MFMA16(qf0, kst[kb][0], s0);
        s0 = MFMA16(qf1, kst[kb][1], s0);
        s1 = MFMA16(qf2, kst[kb][0], s1);
        s1 = MFMA16(qf3, kst[kb][1], s1);
#pragma unroll
        for (int r = 0; r < 4; ++r) {
          zacc[0][hf * 4 + kb][r] += exp2f(s0[r] * EXP2SCALE);
          zacc[1][hf * 4 + kb][r] += exp2f(s1[r] * EXP2SCALE);
        }
      }
    }
    qbase += PERHEAD / 8;
    kbase += PERHEAD / 8;
  }

#pragma unroll
  for (int sq = 0; sq < 2; ++sq)
#pragma unroll
    for (int kb = 0; kb < 8; ++kb)
#pragma unroll
      for (int r = 0; r < 4; ++r) {
        int q = q0 + wave * 32 + sq * 16 + (lane >> 4) * 4 + r;
        int k = k0 + kb * 16 + (lane & 15);
        union { _Float16 h; unsigned short u; } cv;
        cv.h = (_Float16)log2f(zacc[sq][kb][r]);
        Zl[((size_t)b * S_ + q) * S_ + k] = cv.u;
      }
}

// ---------------- Pass 2: x^T = exp2(s*C - Lz) @ V ----------------
// Block = (q-tile 64, h, b). S computed TRANSPOSED (m=key, n=q). Two 64-key tiles
// per barrier epoch; P double-buffered -> 1 barrier/epoch. 1/Z folded into the
// exponent (Lz = log2(Z), fp16): P = exp2(fma(s, C, -Lz)) — one fma + one exp per
// element, packed to bf16 pairs via +0x8000 + v_perm (round-half-up).
__launch_bounds__(256, 3)
__global__ void attn_pv(const unsigned short* __restrict__ Qf,
                        const unsigned short* __restrict__ Kf,
                        const unsigned short* __restrict__ Vf,
                        const unsigned short* __restrict__ Zl,
                        unsigned short* __restrict__ X) {
  __shared__ unsigned short lP[2 * 8192];  // 2 bufs x 2 tiles x 4096 ushort
  const int tid = threadIdx.x, lane = tid & 63, wave = tid >> 6;
  const int h = blockIdx.x, b = blockIdx.z;
  const int q0 = blockIdx.y * 64;

  const size_t headf = (size_t)(b * H_ + h) * (PERHEAD / 8);  // short8 units
  short8 qf[4][2];
#pragma unroll
  for (int qb = 0; qb < 4; ++qb) {
    const short8* qp = (const short8*)Qf + headf + ((q0 >> 4) + qb) * 128 + lane;
    qf[qb][0] = qp[0];
    qf[qb][1] = qp[64];
  }
  const short8* kp = (const short8*)Kf + headf + wave * 128 + lane;  // += 1024/epoch
  const short8* vp = (const short8*)Vf + headf + wave * 64 + lane;   // += 1024/epoch
  const unsigned short* zp = Zl + ((size_t)b * S_ + q0 + (lane & 15)) * S_
                             + wave * 16 + ((lane >> 4) << 2);

  // P write offset within a 4096-ushort tile region (fragment-ordered)
  const int pw_off = ((wave >> 1) << 9)
                   + (((lane & 15) | (((wave & 1) << 1 | ((lane >> 4) >> 1)) << 4)) << 3)
                   + (((lane >> 4) & 1) << 2);

  floatx4 xacc[4] = {};  // x^T[dk = wave*16 + row][q = qb*16 + col]

  for (int kt2 = 0; kt2 < S_ / 128; ++kt2) {
    const int buf = (kt2 & 1) << 13;  // 8192 ushort per buffer
    // global fragment loads for BOTH tiles (independent -> deep in flight)
    short8 kA0 = kp[0],   kA1 = kp[64];
    short8 kB0 = kp[512], kB1 = kp[576];
    short8 vA0 = vp[0],   vA1 = vp[256];
    short8 vB0 = vp[512], vB1 = vp[768];
    uint2 zzA[4], zzB[4];
#pragma unroll
    for (int qb = 0; qb < 4; ++qb) {
      zzA[qb] = *(const uint2*)(zp + (size_t)(qb * 16) * S_);
      zzB[qb] = *(const uint2*)(zp + (size_t)(qb * 16) * S_ + 64);
    }

    // tile A: S^T, exp2(fma), P -> lP[buf + 0]
    {
      floatx4 sacc[4] = {};
#pragma unroll
      for (int qb = 0; qb < 4; ++qb) {
        sacc[qb] = MFMA16(kA0, qf[qb][0], sacc[qb]);
        sacc[qb] = MFMA16(kA1, qf[qb][1], sacc[qb]);
      }
#pragma unroll
      for (int qb = 0; qb < 4; ++qb) {
        union { uint2 v; _Float16 hv[4]; } za; za.v = zzA[qb];
        float e0 = exp2f(fmaf(sacc[qb][0], EXP2SCALE, -(float)za.hv[0]));
        float e1 = exp2f(fmaf(sacc[qb][1], EXP2SCALE, -(float)za.hv[1]));
        float e2 = exp2f(fmaf(sacc[qb][2], EXP2SCALE, -(float)za.hv[2]));
        float e3 = exp2f(fmaf(sacc[qb][3], EXP2SCALE, -(float)za.hv[3]));
        uint2 p;
        p.x = pack_bf16_rhu(e0, e1);
        p.y = pack_bf16_rhu(e2, e3);
        *(uint2*)&lP[buf + (qb << 10) + pw_off] = p;
      }
    }
    // tile B: S^T, exp2(fma), P -> lP[buf + 4096]
    {
      floatx4 sacc[4] = {};
#pragma unroll
      for (int qb = 0; qb < 4; ++qb) {
        sacc[qb] = MFMA16(kB0, qf[qb][0], sacc[qb]);
        sacc[qb] = MFMA16(kB1, qf[qb][1], sacc[qb]);
      }
#pragma unroll
      for (int qb = 0; qb < 4; ++qb) {
        union { uint2 v; _Float16 hv[4]; } zb; zb.v = zzB[qb];
        float e0 = exp2f(fmaf(sacc[qb][0], EXP2SCALE, -(float)zb.hv[0]));
        float e1 = exp2f(fmaf(sacc[qb][1], EXP2SCALE, -(float)zb.hv[1]));
        float e2 = exp2f(fmaf(sacc[qb][2], EXP2SCALE, -(float)zb.hv[2]));
        float e3 = exp2f(fmaf(sacc[qb][3], EXP2SCALE, -(float)zb.hv[3]));
        uint2 p;
        p.x = pack_bf16_rhu(e0, e1);
        p.y = pack_bf16_rhu(e2, e3);
        *(uint2*)&lP[buf + 4096 + (qb << 10) + pw_off] = p;
      }
    }
    __syncthreads();

    // PV for both tiles
#pragma unroll
    for (int qb = 0; qb < 4; ++qb) {
      short8 pA0 = *(const short8*)&lP[buf + (qb << 10) + (lane << 3)];
      short8 pA1 = *(const short8*)&lP[buf + (qb << 10) + 512 + (lane << 3)];
      short8 pB0 = *(const short8*)&lP[buf + 4096 + (qb << 10) + (lane << 3)];
      short8 pB1 = *(const short8*)&lP[buf + 4096 + (qb << 10) + 512 + (lane << 3)];
      xacc[qb] = MFMA16(vA0, pA0, xacc[qb]);
      xacc[qb] = MFMA16(vA1, pA1, xacc[qb]);
      xacc[qb] = MFMA16(vB0, pB0, xacc[qb]);
      xacc[qb] = MFMA16(vB1, pB1, xacc[qb]);
    }

    kp += 1024;  // 128 keys = 8 sblks x 2 frags x 64 short8
    vp += 1024;  // 4 kblks x 4 frags x 64 short8
    zp += 128;
  }

  // epilogue: transpose x^T -> x via padded LDS, then coalesced 16B stores
  __syncthreads();
  unsigned short* lX = lP;  // 64 rows(q) x 72 (dk padded)
#pragma unroll
  for (int qb = 0; qb < 4; ++qb)
#pragma unroll
    for (int r = 0; r < 4; ++r) {
      int q  = qb * 16 + (lane & 15);
      int dk = wave * 16 + (lane >> 4) * 4 + r;
      lX[q * 72 + dk] = f2bf(xacc[qb][r]);
    }
  __syncthreads();
  {
    int q = tid >> 2, cg = (tid & 3) * 16;
    short8 v0 = *(const short8*)&lX[q * 72 + cg];
    short8 v1 = *(const short8*)&lX[q * 72 + cg + 8];
    unsigned short* o = X + (size_t)(b * S_ + q0 + q) * D_ + h * DK_ + cg;
    *(short8*)&o[0] = v0;
    *(short8*)&o[8] = v1;
  }
}

// ---------------- launch ----------------
extern "C" void kernel_launch(void* const* d_in, const int* in_sizes, int n_in,
                              void* d_out, int out_size, void* d_ws, size_t ws_size,
                              hipStream_t stream) {
  const float* qi = (const float*)d_in[0];
  const float* ki = (const float*)d_in[1];
  const float* vi = (const float*)d_in[2];
  // d_in[3] = mask: reference discards masked_fill result -> unused
  const float* Wq = (const float*)d_in[4];
  const float* Wk = (const float*)d_in[5];
  const float* Wv = (const float*)d_in[6];
  const float* Wo = (const float*)d_in[7];

  const size_t NT = (size_t)B_ * S_ * D_;  // 4,194,304
  const size_t NW = (size_t)D_ * D_;       // 1,048,576

  unsigned short* w = (unsigned short*)d_ws;
  unsigned short* qi_bf = w; w += NT;
  unsigned short* ki_bf = w; w += NT;
  unsigned short* vi_bf = w; w += NT;
  unsigned short* Wq_bf = w; w += NW;
  unsigned short* Wk_bf = w; w += NW;
  unsigned short* Wv_bf = w; w += NW;
  unsigned short* Wo_bf = w; w += NW;
  unsigned short* Qf = w; w += NT;  // fragment-ordered per (b,h)
  unsigned short* Kf = w; w += NT;
  unsigned short* Vf = w; w += NT;
  unsigned short* Xb = w; w += NT;  // [b,s,e] row-major bf16
  unsigned short* Zl = w;           // [b,q,k] fp16 log2(Z), 16 MiB

  {
    int n4 = (int)(NT / 4);   // 1048576 -> 4096 blocks
    cast3_f32_bf16<<<dim3((n4 + 255) / 256, 1, 3), 256, 0, stream>>>(
        qi, ki, vi, qi_bf, ki_bf, vi_bf, n4);
    int n4w = (int)(NW / 4);  // 262144 -> 1024 blocks
    cast4_f32_bf16<<<dim3((n4w + 255) / 256, 1, 4), 256, 0, stream>>>(
        Wq, Wk, Wv, Wo, Wq_bf, Wk_bf, Wv_bf, Wo_bf, n4w);
  }

  gemm_qkv<<<dim3(D_ / 128, (B_ * S_) / 128, 3), 256, 0, stream>>>(
      qi_bf, ki_bf, vi_bf, Wq_bf, Wk_bf, Wv_bf, Qf, Kf, Vf);

  compute_z<<<dim3(S_ / 128, S_ / 128, B_), 256, 0, stream>>>(Qf, Kf, Zl);
  attn_pv<<<dim3(H_, S_ / 64, B_), 256, 0, stream>>>(Qf, Kf, Vf, Zl, Xb);

  gemm_out<<<dim3(D_ / 128, (B_ * S_) / 128), 256, 0, stream>>>(Xb, Wo_bf, (float*)d_out);
}